// Round 1
// baseline (214.074 us; speedup 1.0000x reference)
//
#include <hip/hip_runtime.h>
#include <hip/hip_bf16.h>

#define NNODE 1024
#define DIM 128
#define HEADS 8
#define DK 16
#define EDIM 16
#define TN 2          // target nodes per block in attention kernel
#define TM 32         // source-node chunk staged in LDS

// ---------------- Kernel 1: LayerNorm + QKV projection ----------------
__global__ __launch_bounds__(128)
void ln_qkv_kernel(const float* __restrict__ x,
                   const float* __restrict__ Wq, const float* __restrict__ bq,
                   const float* __restrict__ Wk, const float* __restrict__ bk,
                   const float* __restrict__ Wv, const float* __restrict__ bv,
                   const float* __restrict__ gamma, const float* __restrict__ beta,
                   float* __restrict__ qg, float* __restrict__ kg, float* __restrict__ vg) {
    const int n = blockIdx.x;
    const int t = threadIdx.x;
    __shared__ float sb[DIM];
    __shared__ float hrow[DIM];

    float xv = x[n * DIM + t];
    sb[t] = xv;
    __syncthreads();
    #pragma unroll
    for (int off = 64; off > 0; off >>= 1) {
        if (t < off) sb[t] += sb[t + off];
        __syncthreads();
    }
    float mu = sb[0] * (1.0f / DIM);
    __syncthreads();
    float dx = xv - mu;
    sb[t] = dx * dx;
    __syncthreads();
    #pragma unroll
    for (int off = 64; off > 0; off >>= 1) {
        if (t < off) sb[t] += sb[t + off];
        __syncthreads();
    }
    float var = sb[0] * (1.0f / DIM);
    float rs = rsqrtf(var + 1e-5f);
    hrow[t] = dx * rs * gamma[t] + beta[t];
    __syncthreads();

    float aq = bq[t], ak = bk[t], av = bv[t];
    #pragma unroll 8
    for (int i = 0; i < DIM; ++i) {
        float hv = hrow[i];
        aq = fmaf(hv, Wq[i * DIM + t], aq);
        ak = fmaf(hv, Wk[i * DIM + t], ak);
        av = fmaf(hv, Wv[i * DIM + t], av);
    }
    qg[n * DIM + t] = aq;
    kg[n * DIM + t] = ak;
    vg[n * DIM + t] = av;
}

// ---------------- Kernel 2: fused edge-biased attention ----------------
// grid = NNODE/TN blocks, 256 threads = (head: tid>>5, mslot: tid&31)
__global__ __launch_bounds__(256, 2)
void attn_kernel(const float* __restrict__ qg, const float* __restrict__ kg,
                 const float* __restrict__ vg, const float* __restrict__ ef,
                 const int* __restrict__ mask,
                 const float* __restrict__ Wae, const float* __restrict__ bae,
                 const float* __restrict__ Wve, const float* __restrict__ bve,
                 float* __restrict__ Og) {
    const int t = threadIdx.x;
    const int h = t >> 5;
    const int s = t & 31;
    const int n0 = blockIdx.x * TN;

    __shared__ float ef_lds[TN][TM][EDIM + 1];  // pad -> <=2-way bank conflicts (free)
    __shared__ int   mk_lds[TN][TM];
    __shared__ float red_sl[TN][HEADS];
    __shared__ float red_av[TN][HEADS][DK];
    __shared__ float red_aT[TN][HEADS][EDIM];

    // per-thread constants
    float qreg[TN][DK];
    #pragma unroll
    for (int n = 0; n < TN; ++n) {
        const float* qp = qg + (size_t)(n0 + n) * DIM + h * DK;
        #pragma unroll
        for (int d4 = 0; d4 < 4; ++d4) {
            float4 qv = *(const float4*)(qp + d4 * 4);
            qreg[n][d4 * 4 + 0] = qv.x; qreg[n][d4 * 4 + 1] = qv.y;
            qreg[n][d4 * 4 + 2] = qv.z; qreg[n][d4 * 4 + 3] = qv.w;
        }
    }
    float waec[EDIM];
    #pragma unroll
    for (int e = 0; e < EDIM; ++e) waec[e] = Wae[e * HEADS + h];
    const float baeh = bae[h];

    float sl[TN];
    float accv[TN][DK];
    float accT[TN][EDIM];
    #pragma unroll
    for (int n = 0; n < TN; ++n) {
        sl[n] = 0.f;
        #pragma unroll
        for (int d = 0; d < DK; ++d) accv[n][d] = 0.f;
        #pragma unroll
        for (int e = 0; e < EDIM; ++e) accT[n][e] = 0.f;
    }

    for (int c = 0; c < NNODE / TM; ++c) {
        const int mbase = c * TM;
        __syncthreads();
        {   // stage ef chunk: TN*TM*EDIM = 1024 floats = 256 float4, one per thread
            int sn = t >> 7;
            int r = t & 127;
            int ml = r >> 2;
            int e4 = (r & 3) * 4;
            const float* src = ef + (((size_t)(n0 + sn) * NNODE) + (mbase + ml)) * EDIM + e4;
            float4 val = *(const float4*)src;
            float* dst = &ef_lds[sn][ml][e4];
            dst[0] = val.x; dst[1] = val.y; dst[2] = val.z; dst[3] = val.w;
            if (t < TN * TM) {
                int nn = t >> 5, mm = t & 31;
                mk_lds[nn][mm] = mask[(size_t)(n0 + nn) * NNODE + mbase + mm];
            }
        }
        __syncthreads();

        const int m = mbase + s;
        float kk[DK], vv[DK];
        const float* kp = kg + (size_t)m * DIM + h * DK;
        const float* vp = vg + (size_t)m * DIM + h * DK;
        #pragma unroll
        for (int d4 = 0; d4 < 4; ++d4) {
            float4 k4 = *(const float4*)(kp + d4 * 4);
            kk[d4 * 4 + 0] = k4.x; kk[d4 * 4 + 1] = k4.y;
            kk[d4 * 4 + 2] = k4.z; kk[d4 * 4 + 3] = k4.w;
            float4 v4 = *(const float4*)(vp + d4 * 4);
            vv[d4 * 4 + 0] = v4.x; vv[d4 * 4 + 1] = v4.y;
            vv[d4 * 4 + 2] = v4.z; vv[d4 * 4 + 3] = v4.w;
        }

        #pragma unroll
        for (int n = 0; n < TN; ++n) {
            float efv[EDIM];
            #pragma unroll
            for (int e = 0; e < EDIM; ++e) efv[e] = ef_lds[n][s][e];
            float bias = baeh;
            float dot = 0.f;
            #pragma unroll
            for (int e = 0; e < EDIM; ++e) bias = fmaf(efv[e], waec[e], bias);
            #pragma unroll
            for (int d = 0; d < DK; ++d) dot = fmaf(qreg[n][d], kk[d], dot);
            float logit = dot * 0.25f + bias;   // 1/sqrt(16)
            // masked -> exp(-10000) == 0 in fp32, identical to reference
            float p = mk_lds[n][s] ? __expf(logit) : 0.f;
            sl[n] += p;
            #pragma unroll
            for (int d = 0; d < DK; ++d) accv[n][d] = fmaf(p, vv[d], accv[n][d]);
            #pragma unroll
            for (int e = 0; e < EDIM; ++e) accT[n][e] = fmaf(p, efv[e], accT[n][e]);
        }
    }

    // butterfly all-reduce over the 32 m-slots of this head group
    #pragma unroll
    for (int n = 0; n < TN; ++n) {
        #pragma unroll
        for (int off = 16; off >= 1; off >>= 1) {
            sl[n] += __shfl_xor(sl[n], off);
            #pragma unroll
            for (int d = 0; d < DK; ++d) accv[n][d] += __shfl_xor(accv[n][d], off);
            #pragma unroll
            for (int e = 0; e < EDIM; ++e) accT[n][e] += __shfl_xor(accT[n][e], off);
        }
        if (s == 0) {
            red_sl[n][h] = sl[n];
            #pragma unroll
            for (int d = 0; d < DK; ++d) red_av[n][h][d] = accv[n][d];
            #pragma unroll
            for (int e = 0; e < EDIM; ++e) red_aT[n][h][e] = accT[n][e];
        }
    }
    __syncthreads();

    // epilogue: O[n, c] = (accv[d] + sum_e accT[e]*Wve[e,c]) / sl + bve[c]
    {
        int n = t >> 7;
        int col = t & 127;
        int hh = col >> 4;
        int dd = col & 15;
        float inv = 1.0f / red_sl[n][hh];
        float o = red_av[n][hh][dd];
        float acc2 = 0.f;
        #pragma unroll
        for (int e = 0; e < EDIM; ++e) acc2 = fmaf(red_aT[n][hh][e], Wve[e * DIM + col], acc2);
        o = (o + acc2) * inv + bve[col];
        Og[(size_t)(n0 + n) * DIM + col] = o;
    }
}

// ---------------- Kernel 3: output projection + residual ----------------
__global__ __launch_bounds__(128)
void out_proj_kernel(const float* __restrict__ x, const float* __restrict__ O,
                     const float* __restrict__ Wo, const float* __restrict__ bo,
                     float* __restrict__ out) {
    const int n = blockIdx.x;
    const int t = threadIdx.x;
    __shared__ float orow[DIM];
    orow[t] = O[n * DIM + t];
    __syncthreads();
    float acc = bo[t] + x[n * DIM + t];
    #pragma unroll 8
    for (int i = 0; i < DIM; ++i) acc = fmaf(orow[i], Wo[i * DIM + t], acc);
    out[n * DIM + t] = acc;
}

extern "C" void kernel_launch(void* const* d_in, const int* in_sizes, int n_in,
                              void* d_out, int out_size, void* d_ws, size_t ws_size,
                              hipStream_t stream) {
    const float* x     = (const float*)d_in[0];
    const float* ef    = (const float*)d_in[1];
    const int*   mask  = (const int*)d_in[2];
    const float* Wq    = (const float*)d_in[3];
    const float* bq    = (const float*)d_in[4];
    const float* Wk    = (const float*)d_in[5];
    const float* bk    = (const float*)d_in[6];
    const float* Wv    = (const float*)d_in[7];
    const float* bv    = (const float*)d_in[8];
    const float* Wae   = (const float*)d_in[9];
    const float* bae   = (const float*)d_in[10];
    const float* Wve   = (const float*)d_in[11];
    const float* bve   = (const float*)d_in[12];
    const float* Wo    = (const float*)d_in[13];
    const float* bo    = (const float*)d_in[14];
    const float* gamma = (const float*)d_in[15];
    const float* beta  = (const float*)d_in[16];

    float* ws = (float*)d_ws;
    float* qg = ws;
    float* kg = ws + (size_t)NNODE * DIM;
    float* vg = ws + (size_t)2 * NNODE * DIM;
    float* Og = ws + (size_t)3 * NNODE * DIM;

    ln_qkv_kernel<<<NNODE, DIM, 0, stream>>>(x, Wq, bq, Wk, bk, Wv, bv, gamma, beta, qg, kg, vg);
    attn_kernel<<<NNODE / TN, 256, 0, stream>>>(qg, kg, vg, ef, mask, Wae, bae, Wve, bve, Og);
    out_proj_kernel<<<NNODE, DIM, 0, stream>>>(x, Og, Wo, bo, d_out ? (float*)d_out : nullptr);
}

// Round 2
// 209.428 us; speedup vs baseline: 1.0222x; 1.0222x over previous
//
#include <hip/hip_runtime.h>
#include <hip/hip_bf16.h>

#define NNODE 1024
#define DIM 128
#define HEADS 8
#define DK 16
#define EDIM 16
#define TM 32         // source-node chunk staged in LDS

// ---------------- Kernel 1: LayerNorm + QKV projection ----------------
// 1024 blocks x 384 threads: t>>7 selects q/k/v, t&127 is the output column.
__global__ __launch_bounds__(384)
void ln_qkv_kernel(const float* __restrict__ x,
                   const float* __restrict__ Wq, const float* __restrict__ bq,
                   const float* __restrict__ Wk, const float* __restrict__ bk,
                   const float* __restrict__ Wv, const float* __restrict__ bv,
                   const float* __restrict__ gamma, const float* __restrict__ beta,
                   float* __restrict__ qg, float* __restrict__ kg, float* __restrict__ vg) {
    const int n = blockIdx.x;
    const int t = threadIdx.x;
    __shared__ float hrow[DIM];
    __shared__ float part[4];

    float xv = 0.f;
    if (t < 128) {
        xv = x[n * DIM + t];
        float v = xv;
        #pragma unroll
        for (int off = 32; off >= 1; off >>= 1) v += __shfl_xor(v, off);
        if ((t & 63) == 0) part[t >> 6] = v;
    }
    __syncthreads();
    const float mu = (part[0] + part[1]) * (1.0f / DIM);
    const float dx = xv - mu;
    if (t < 128) {
        float v = dx * dx;
        #pragma unroll
        for (int off = 32; off >= 1; off >>= 1) v += __shfl_xor(v, off);
        if ((t & 63) == 0) part[2 + (t >> 6)] = v;
    }
    __syncthreads();
    if (t < 128) {
        const float var = (part[2] + part[3]) * (1.0f / DIM);
        hrow[t] = dx * rsqrtf(var + 1e-5f) * gamma[t] + beta[t];
    }
    __syncthreads();

    const int which = t >> 7;          // 0,1,2 -> q,k,v (wave-uniform)
    const int col = t & 127;
    const float* W = (which == 0) ? Wq : (which == 1) ? Wk : Wv;
    const float* b = (which == 0) ? bq : (which == 1) ? bk : bv;
    float* o       = (which == 0) ? qg : (which == 1) ? kg : vg;
    float acc = b[col];
    #pragma unroll 16
    for (int i = 0; i < DIM; ++i) acc = fmaf(hrow[i], W[i * DIM + col], acc);
    o[n * DIM + col] = acc;
}

// ---------------- Kernel 2: fused attention + output proj + residual ----------------
// grid = NNODE blocks (one target node each), 256 threads = (s: t>>3, h: t&7)
__global__ __launch_bounds__(256, 4)
void attn_kernel(const float* __restrict__ qg, const float* __restrict__ kg,
                 const float* __restrict__ vg, const float* __restrict__ ef,
                 const int* __restrict__ mask,
                 const float* __restrict__ Wae, const float* __restrict__ bae,
                 const float* __restrict__ Wve, const float* __restrict__ bve,
                 const float* __restrict__ x,
                 const float* __restrict__ Wo, const float* __restrict__ bo,
                 float* __restrict__ out) {
    const int t = threadIdx.x;
    const int h = t & 7;
    const int s = t >> 3;      // 0..31
    const int wid = t >> 6;    // wave id 0..3
    const int lane = t & 63;
    const int n = blockIdx.x;

    __shared__ float ef_lds[TM][20];   // stride 20 floats: 16B aligned, conflict-free b128
    __shared__ int   mk_lds[TM];
    __shared__ float r_sl[4][HEADS];
    __shared__ float r_av[4][HEADS][DK];
    __shared__ float r_aT[4][HEADS][EDIM];
    __shared__ float c_sl[HEADS];
    __shared__ float c_av[HEADS][DK];
    __shared__ float c_aT[HEADS][EDIM];
    __shared__ float orow[DIM];
    __shared__ float ph[2][DIM];

    // per-thread constants
    float qreg[DK];
    {
        const float* qp = qg + (size_t)n * DIM + h * DK;
        #pragma unroll
        for (int d4 = 0; d4 < 4; ++d4) {
            float4 qv = *(const float4*)(qp + d4 * 4);
            qreg[d4 * 4 + 0] = qv.x; qreg[d4 * 4 + 1] = qv.y;
            qreg[d4 * 4 + 2] = qv.z; qreg[d4 * 4 + 3] = qv.w;
        }
    }
    float waec[EDIM];
    #pragma unroll
    for (int e = 0; e < EDIM; ++e) waec[e] = Wae[e * HEADS + h];
    const float baeh = bae[h];

    float sl = 0.f;
    float accv[DK];
    float accT[EDIM];
    #pragma unroll
    for (int d = 0; d < DK; ++d) accv[d] = 0.f;
    #pragma unroll
    for (int e = 0; e < EDIM; ++e) accT[e] = 0.f;

    for (int c = 0; c < NNODE / TM; ++c) {
        const int mbase = c * TM;
        __syncthreads();
        if (t < 128) {
            // 32 rows x 16 floats = 128 float4, one per thread, fully coalesced
            const int ml = t >> 2;
            const int e4 = (t & 3) * 4;
            const float* src = ef + (((size_t)n * NNODE) + (mbase + ml)) * EDIM + e4;
            float4 val = *(const float4*)src;
            *(float4*)&ef_lds[ml][e4] = val;
        } else if (t < 160) {
            mk_lds[t - 128] = mask[(size_t)n * NNODE + mbase + (t - 128)];
        }
        __syncthreads();

        const int m = mbase + s;
        float kk[DK], vv[DK];
        const float* kp = kg + (size_t)m * DIM + h * DK;
        const float* vp = vg + (size_t)m * DIM + h * DK;
        #pragma unroll
        for (int d4 = 0; d4 < 4; ++d4) {
            float4 k4 = *(const float4*)(kp + d4 * 4);
            kk[d4 * 4 + 0] = k4.x; kk[d4 * 4 + 1] = k4.y;
            kk[d4 * 4 + 2] = k4.z; kk[d4 * 4 + 3] = k4.w;
            float4 v4 = *(const float4*)(vp + d4 * 4);
            vv[d4 * 4 + 0] = v4.x; vv[d4 * 4 + 1] = v4.y;
            vv[d4 * 4 + 2] = v4.z; vv[d4 * 4 + 3] = v4.w;
        }

        float efv[EDIM];
        #pragma unroll
        for (int e4 = 0; e4 < 4; ++e4) {
            float4 ev = *(const float4*)&ef_lds[s][e4 * 4];
            efv[e4 * 4 + 0] = ev.x; efv[e4 * 4 + 1] = ev.y;
            efv[e4 * 4 + 2] = ev.z; efv[e4 * 4 + 3] = ev.w;
        }
        float bias = baeh;
        float dot = 0.f;
        #pragma unroll
        for (int e = 0; e < EDIM; ++e) bias = fmaf(efv[e], waec[e], bias);
        #pragma unroll
        for (int d = 0; d < DK; ++d) dot = fmaf(qreg[d], kk[d], dot);
        const float logit = dot * 0.25f + bias;   // 1/sqrt(16)
        // masked -> exp(-10000) == 0 in fp32, identical to reference
        const float p = mk_lds[s] ? __expf(logit) : 0.f;
        sl += p;
        #pragma unroll
        for (int d = 0; d < DK; ++d) accv[d] = fmaf(p, vv[d], accv[d]);
        #pragma unroll
        for (int e = 0; e < EDIM; ++e) accT[e] = fmaf(p, efv[e], accT[e]);
    }

    // reduce over the 8 s-slots within each wave (lane bits 3,4,5)
    #pragma unroll
    for (int off = 8; off <= 32; off <<= 1) {
        sl += __shfl_xor(sl, off);
        #pragma unroll
        for (int d = 0; d < DK; ++d) accv[d] += __shfl_xor(accv[d], off);
        #pragma unroll
        for (int e = 0; e < EDIM; ++e) accT[e] += __shfl_xor(accT[e], off);
    }
    if ((lane & 56) == 0) {   // lanes 0..7 of each wave; h == lane
        r_sl[wid][h] = sl;
        #pragma unroll
        for (int d = 0; d < DK; ++d) r_av[wid][h][d] = accv[d];
        #pragma unroll
        for (int e = 0; e < EDIM; ++e) r_aT[wid][h][e] = accT[e];
    }
    __syncthreads();

    // combine the 4 wave-partials: 8 heads x 33 elems = 264 slots
    for (int u = t; u < HEADS * 33; u += 256) {
        const int hh = u / 33;
        const int j = u % 33;
        float v = 0.f;
        if (j == 0) {
            #pragma unroll
            for (int w = 0; w < 4; ++w) v += r_sl[w][hh];
            c_sl[hh] = v;
        } else if (j <= 16) {
            const int d = j - 1;
            #pragma unroll
            for (int w = 0; w < 4; ++w) v += r_av[w][hh][d];
            c_av[hh][d] = v;
        } else {
            const int e = j - 17;
            #pragma unroll
            for (int w = 0; w < 4; ++w) v += r_aT[w][hh][e];
            c_aT[hh][e] = v;
        }
    }
    __syncthreads();

    // attention epilogue -> O row in LDS
    if (t < 128) {
        const int col = t;
        const int hh = col >> 4;
        const int dd = col & 15;
        const float inv = 1.0f / c_sl[hh];
        float acc2 = 0.f;
        #pragma unroll
        for (int e = 0; e < EDIM; ++e) acc2 = fmaf(c_aT[hh][e], Wve[e * DIM + col], acc2);
        orow[col] = (c_av[hh][dd] + acc2) * inv + bve[col];
    }
    __syncthreads();

    // fused output projection + residual: split i-range over two halves
    {
        const int col = t & 127;
        const int half = t >> 7;
        float acc = 0.f;
        const float* wp = Wo + (size_t)(half * 64) * DIM + col;
        #pragma unroll 16
        for (int i = 0; i < 64; ++i) acc = fmaf(orow[half * 64 + i], wp[i * DIM], acc);
        ph[half][col] = acc;
    }
    __syncthreads();
    if (t < 128) {
        out[(size_t)n * DIM + t] = x[(size_t)n * DIM + t] + bo[t] + ph[0][t] + ph[1][t];
    }
}

extern "C" void kernel_launch(void* const* d_in, const int* in_sizes, int n_in,
                              void* d_out, int out_size, void* d_ws, size_t ws_size,
                              hipStream_t stream) {
    const float* x     = (const float*)d_in[0];
    const float* ef    = (const float*)d_in[1];
    const int*   mask  = (const int*)d_in[2];
    const float* Wq    = (const float*)d_in[3];
    const float* bq    = (const float*)d_in[4];
    const float* Wk    = (const float*)d_in[5];
    const float* bk    = (const float*)d_in[6];
    const float* Wv    = (const float*)d_in[7];
    const float* bv    = (const float*)d_in[8];
    const float* Wae   = (const float*)d_in[9];
    const float* bae   = (const float*)d_in[10];
    const float* Wve   = (const float*)d_in[11];
    const float* bve   = (const float*)d_in[12];
    const float* Wo    = (const float*)d_in[13];
    const float* bo    = (const float*)d_in[14];
    const float* gamma = (const float*)d_in[15];
    const float* beta  = (const float*)d_in[16];

    float* ws = (float*)d_ws;
    float* qg = ws;
    float* kg = ws + (size_t)NNODE * DIM;
    float* vg = ws + (size_t)2 * NNODE * DIM;

    ln_qkv_kernel<<<NNODE, 384, 0, stream>>>(x, Wq, bq, Wk, bk, Wv, bv, gamma, beta, qg, kg, vg);
    attn_kernel<<<NNODE, 256, 0, stream>>>(qg, kg, vg, ef, mask, Wae, bae, Wve, bve,
                                           x, Wo, bo, (float*)d_out);
}